// Round 16
// baseline (538.307 us; speedup 1.0000x reference)
//
#include <hip/hip_runtime.h>
#include <hip/hip_bf16.h>

typedef short v8s __attribute__((ext_vector_type(8)));
typedef float v4f __attribute__((ext_vector_type(4)));
typedef unsigned long long u64;

#define ALPHA 0.2f

__device__ inline unsigned short f32_bf16(float x){
    unsigned int u = __float_as_uint(x);
    unsigned int r = (u + 0x7fffu + ((u >> 16) & 1u)) >> 16;
    return (unsigned short)r;
}
__device__ inline float bf16_f32(unsigned short s){
    return __uint_as_float(((unsigned int)s) << 16);
}
__device__ inline v4f mfma16(v8s a, v8s b, v4f c){
    return __builtin_amdgcn_mfma_f32_16x16x32_bf16(a, b, c, 0, 0, 0);
}
// async global->LDS, 16B per lane; lds ptr must be wave-uniform base (lane*16 added by HW)
__device__ inline void gload16(const unsigned short* g, short* l){
    __builtin_amdgcn_global_load_lds((const __attribute__((address_space(1))) unsigned int*)g,
                                     (__attribute__((address_space(3))) unsigned int*)l,
                                     16, 0, 0);
}
#define VMCNT0   asm volatile("s_waitcnt vmcnt(0)" ::: "memory")
#define CFENCE   asm volatile("" ::: "memory")

// ---------------- conversions -------------------------------------------

__global__ void k_convert_x(const float* __restrict__ x, v8s* __restrict__ out, int n8){
    int i = blockIdx.x * 256 + threadIdx.x;
    if (i >= n8) return;
    const float4* p = (const float4*)x + (size_t)i * 2;
    float4 a = p[0], b = p[1];
    v8s r;
    r[0] = (short)f32_bf16(a.x); r[1] = (short)f32_bf16(a.y);
    r[2] = (short)f32_bf16(a.z); r[3] = (short)f32_bf16(a.w);
    r[4] = (short)f32_bf16(b.x); r[5] = (short)f32_bf16(b.y);
    r[6] = (short)f32_bf16(b.z); r[7] = (short)f32_bf16(b.w);
    out[i] = r;
}

// W_all[g][k][h] f32 -> Wt[g][h][k] bf16   (g = t*3+l, 9 x 1024 x 512)
__global__ void k_transpose_w(const float* __restrict__ W, unsigned short* __restrict__ Wt){
    __shared__ float tile[32][33];
    int g = blockIdx.z, k0 = blockIdx.x * 32, h0 = blockIdx.y * 32;
    int tx = threadIdx.x, ty = threadIdx.y;           // 32 x 8
    #pragma unroll
    for (int i = 0; i < 4; ++i)
        tile[ty + i*8][tx] = W[((size_t)g*1024 + k0 + ty + i*8)*512 + h0 + tx];
    __syncthreads();
    #pragma unroll
    for (int i = 0; i < 4; ++i){
        int h = ty + i*8;
        Wt[((size_t)g*512 + h0 + h)*1024 + k0 + tx] = f32_bf16(tile[tx][h]);
    }
}

__global__ void k_wawat(const float* __restrict__ w, unsigned short* __restrict__ wt){
    int i = blockIdx.x * 256 + threadIdx.x;           // c*512 + k
    if (i >= 128 * 512) return;
    int c = i >> 9, k = i & 511;
    wt[i] = (c < 100) ? f32_bf16(w[k*100 + c]) : (unsigned short)0;
}

// ---------------- adjacency bitsets -------------------------------------

// 4 rows per block (one per wave)
__global__ __launch_bounds__(256) void k_bits(const float* __restrict__ adj,
                                              u64* __restrict__ bits){
    int row = blockIdx.x * 4 + (threadIdx.x >> 6);    // 0..49151, t-major
    int t = row >> 14, b = (row >> 9) & 31, i = row & 511;
    const float* src = adj + (((size_t)b*3 + t)*512 + i)*512;
    int lane = threadIdx.x & 63;
    #pragma unroll
    for (int w = 0; w < 8; ++w){
        u64 word = __ballot(src[w*64 + lane] > 0.5f);
        if (lane == 0) bits[(size_t)row*8 + w] = word;
    }
}

// out_row(i) = OR over k set in prev_row(i) of base_row(k); prev kept sparse (A)
__global__ __launch_bounds__(256) void k_boolmm(const u64* __restrict__ prev,
                                                const u64* __restrict__ base,
                                                u64* __restrict__ out){
    int row = blockIdx.x * 256 + threadIdx.x;         // 0..49151
    if (row >= 49152) return;
    int tb = row >> 9;
    const u64* pr = prev + (size_t)row * 8;
    const u64* bb = base + ((size_t)tb << 9) * 8;
    ulonglong2 a0 = {0,0}, a1 = {0,0}, a2 = {0,0}, a3 = {0,0};
    #pragma unroll
    for (int w = 0; w < 8; ++w){
        u64 m = pr[w];
        const u64* bw = bb + (size_t)(w << 6) * 8;
        while (m){
            int k = __builtin_ctzll(m);
            m &= m - 1;
            const ulonglong2* br = (const ulonglong2*)(bw + (size_t)k * 8);
            ulonglong2 b0 = br[0], b1 = br[1], b2 = br[2], b3 = br[3];
            a0.x |= b0.x; a0.y |= b0.y;
            a1.x |= b1.x; a1.y |= b1.y;
            a2.x |= b2.x; a2.y |= b2.y;
            a3.x |= b3.x; a3.y |= b3.y;
        }
    }
    ulonglong2* op = (ulonglong2*)(out + (size_t)row * 8);
    op[0] = a0; op[1] = a1; op[2] = a2; op[3] = a3;
}

// ---------------- Ht = Wt @ X^T + fused f1/f2 partials -------------------
// T3 minimum 2-phase: ping-pong LDS, stage(kt+1) BEFORE compute(kt),
// one vmcnt(0)+s_barrier per step at the END (load latency hides under MFMA)
__global__ __launch_bounds__(256, 4) void k_gemm_h(
    const unsigned short* __restrict__ Wt, const unsigned short* __restrict__ Xb,
    unsigned short* __restrict__ Ht, const float* __restrict__ aall,
    float* __restrict__ f1p, float* __restrict__ f2p, int l)
{
    __shared__ __align__(16) short As0[128*32];
    __shared__ __align__(16) short Bs0[128*32];
    __shared__ __align__(16) short As1[128*32];
    __shared__ __align__(16) short Bs1[128*32];
    const int bn = blockIdx.x, bm = blockIdx.y, t = blockIdx.z;
    const int g = t*3 + l;
    const int tid = threadIdx.x;
    const int lane = tid & 63, wave = tid >> 6;
    const int wr = wave >> 1, wc = wave & 1;
    const int fr = lane & 15, fq = lane >> 4;
    const int slot = fq ^ (fr & 3) ^ ((fr >> 2) & 3);

    const int srow = tid >> 2, sw = tid & 3;
    const int gw = sw ^ (srow & 3) ^ ((srow >> 2) & 3);   // pre-swizzled global word
    const unsigned short* Ap = Wt + ((size_t)g*512 + (size_t)bm*128 + srow)*1024 + gw*8;
    const unsigned short* Bp = Xb + ((size_t)bn*128 + srow)*1024 + gw*8;
    const int wo = wave*512;                          // wave-uniform LDS offset

    v4f acc[4][4] = {};

    // prologue: stage kt=0 into buf0
    gload16(Ap,           As0 + wo);
    gload16(Ap + 64*1024, As0 + wo + 2048);
    gload16(Bp,           Bs0 + wo);
    gload16(Bp + 64*1024, Bs0 + wo + 2048);
    VMCNT0;
    __builtin_amdgcn_s_barrier();
    CFENCE;

    #pragma unroll 2
    for (int kt = 0; kt < 32; ++kt){
        short* cA = (kt & 1) ? As1 : As0;
        short* cB = (kt & 1) ? Bs1 : Bs0;
        if (kt + 1 < 32){                             // issue NEXT tile's loads first
            short* nA = (kt & 1) ? As0 : As1;
            short* nB = (kt & 1) ? Bs0 : Bs1;
            const unsigned short* a1 = Ap + (kt+1)*32;
            const unsigned short* b1 = Bp + (kt+1)*32;
            gload16(a1,           nA + wo);
            gload16(a1 + 64*1024, nA + wo + 2048);
            gload16(b1,           nB + wo);
            gload16(b1 + 64*1024, nB + wo + 2048);
        }
        v8s af[4], bf[4];
        #pragma unroll
        for (int i = 0; i < 4; ++i) af[i] = *(const v8s*)&cA[(wr*64 + i*16 + fr)*32 + slot*8];
        #pragma unroll
        for (int i = 0; i < 4; ++i) bf[i] = *(const v8s*)&cB[(wc*64 + i*16 + fr)*32 + slot*8];
        __builtin_amdgcn_s_setprio(1);
        #pragma unroll
        for (int i = 0; i < 4; ++i)
            #pragma unroll
            for (int j = 0; j < 4; ++j)
                acc[i][j] = mfma16(af[i], bf[j], acc[i][j]);
        __builtin_amdgcn_s_setprio(0);
        VMCNT0;                                       // next tile landed
        __builtin_amdgcn_s_barrier();
        CFENCE;
    }
    // ---- C write ----
    #pragma unroll
    for (int i = 0; i < 4; ++i){
        const int h = bm*128 + wr*64 + i*16 + fq*4;
        #pragma unroll
        for (int j = 0; j < 4; ++j){
            const int mc = bn*128 + wc*64 + j*16 + fr;
            unsigned short* dst = Ht + ((size_t)t*512 + h)*16384 + mc;
            #pragma unroll
            for (int rg = 0; rg < 4; ++rg)
                dst[(size_t)rg*16384] = f32_bf16(acc[i][j][rg]);
        }
    }
    // ---- fused f1/f2 partial epilogue ----
    const float* a1v = aall + ((size_t)t*3 + l)*1024;
    const float* a2v = a1v + 512;
    float s1[4] = {0.f,0.f,0.f,0.f}, s2[4] = {0.f,0.f,0.f,0.f};
    #pragma unroll
    for (int i = 0; i < 4; ++i){
        #pragma unroll
        for (int rg = 0; rg < 4; ++rg){
            const int h = bm*128 + wr*64 + i*16 + fq*4 + rg;
            const float c1 = a1v[h], c2 = a2v[h];
            #pragma unroll
            for (int j = 0; j < 4; ++j){
                s1[j] += acc[i][j][rg]*c1;
                s2[j] += acc[i][j][rg]*c2;
            }
        }
    }
    #pragma unroll
    for (int j = 0; j < 4; ++j){
        s1[j] += __shfl_xor(s1[j], 16); s1[j] += __shfl_xor(s1[j], 32);
        s2[j] += __shfl_xor(s2[j], 16); s2[j] += __shfl_xor(s2[j], 32);
    }
    float* scr = (float*)As0;                         // [2wr][2wc][4j][16fr][2]
    __syncthreads();
    if (fq == 0){
        #pragma unroll
        for (int j = 0; j < 4; ++j){
            scr[(((wr*2 + wc)*4 + j)*16 + fr)*2 + 0] = s1[j];
            scr[(((wr*2 + wc)*4 + j)*16 + fr)*2 + 1] = s2[j];
        }
    }
    __syncthreads();
    if (tid < 256){
        const int which = tid & 1, fr2 = (tid >> 1) & 15, j2 = (tid >> 5) & 3,
                  wc2 = (tid >> 7) & 1;
        const float v = scr[(((0*2 + wc2)*4 + j2)*16 + fr2)*2 + which]
                      + scr[(((1*2 + wc2)*4 + j2)*16 + fr2)*2 + which];
        const int m = bn*128 + wc2*64 + j2*16 + fr2;
        float* dst = which ? f2p : f1p;
        dst[((size_t)bm*3 + t)*16384 + m] = v;
    }
}

// ---------------- masked softmax -> normalized bf16 att rows ------------
// one wave per attention row; sums the 4 bm-partials of f1/f2 inline
__global__ __launch_bounds__(256) void k_soft(
    const float* __restrict__ f1p, const float* __restrict__ f2p,
    const u64* __restrict__ maskP, unsigned short* __restrict__ att)
{
    const int row = blockIdx.x * 4 + (threadIdx.x >> 6);  // (t*32+b)*512 + r
    const int lane = threadIdx.x & 63;
    const int tb = row >> 9;
    const int t = tb >> 5, b = tb & 31;
    const int m1 = b*512 + (row & 511);
    float f1v = 0.f;
    #pragma unroll
    for (int bm = 0; bm < 4; ++bm)
        f1v += f1p[((size_t)bm*3 + t)*16384 + m1];
    const u64 mword = maskP[(size_t)row*8 + (lane >> 3)];
    const unsigned int mbits = (unsigned int)((mword >> ((lane & 7)*8)) & 0xffu);
    const int m2 = b*512 + lane*8;
    float f2v[8] = {0.f,0.f,0.f,0.f,0.f,0.f,0.f,0.f};
    #pragma unroll
    for (int bm = 0; bm < 4; ++bm){
        const float4* fp = (const float4*)(f2p + ((size_t)bm*3 + t)*16384 + m2);
        float4 fa = fp[0], fb = fp[1];
        f2v[0] += fa.x; f2v[1] += fa.y; f2v[2] += fa.z; f2v[3] += fa.w;
        f2v[4] += fb.x; f2v[5] += fb.y; f2v[6] += fb.z; f2v[7] += fb.w;
    }
    float p[8];
    float sm = 0.f;
    #pragma unroll
    for (int u = 0; u < 8; ++u){
        float e = f1v + f2v[u];
        e = (e >= 0.f) ? e : ALPHA*e;
        float pe = (mbits & (1u << u)) ? __expf(e) : 0.f;
        p[u] = pe; sm += pe;
    }
    sm += __shfl_xor(sm, 1);  sm += __shfl_xor(sm, 2);  sm += __shfl_xor(sm, 4);
    sm += __shfl_xor(sm, 8);  sm += __shfl_xor(sm, 16); sm += __shfl_xor(sm, 32);
    const float rinv = 1.f / (sm + 1e-30f);
    v8s pk;
    #pragma unroll
    for (int u = 0; u < 8; ++u) pk[u] = (short)f32_bf16(p[u] * rinv);
    *(v8s*)&att[(size_t)row*512 + lane*8] = pk;
}

// ---------------- PV as batched GEMM, K fused over t (K=1536) -----------
// T3 minimum 2-phase across 48 flattened steps (t=s>>4, kk=s&15);
// grid (32 b, 4 hc, 4 rt) -> b%8 fixes XCD (att+Ht L2-local)
__global__ __launch_bounds__(256, 4) void k_pv(
    const unsigned short* __restrict__ att, const unsigned short* __restrict__ Ht,
    unsigned short* __restrict__ hlb)
{
    __shared__ __align__(16) short As0[128*32];
    __shared__ __align__(16) short Bs0[128*32];
    __shared__ __align__(16) short As1[128*32];
    __shared__ __align__(16) short Bs1[128*32];
    const int b = blockIdx.x, hc = blockIdx.y, rt = blockIdx.z;
    const int tid = threadIdx.x;
    const int lane = tid & 63, wave = tid >> 6;
    const int wr = wave >> 1, wc = wave & 1;
    const int fr = lane & 15, fq = lane >> 4;
    const int slot = fq ^ (fr & 3) ^ ((fr >> 2) & 3);
    const int srow = tid >> 2, sw = tid & 3;
    const int gw = sw ^ (srow & 3) ^ ((srow >> 2) & 3);
    const int wo = wave*512;

    auto aSrc = [&](int s){
        return att + ((size_t)(((s >> 4)*32 + b)*512 + rt*128 + srow))*512
                   + (s & 15)*32 + gw*8;
    };
    auto bSrc = [&](int s){
        return Ht + ((size_t)((s >> 4)*512 + hc*128 + srow))*16384
                  + (size_t)b*512 + (s & 15)*32 + gw*8;
    };

    v4f acc[4][4] = {};

    const unsigned short* a0 = aSrc(0);
    const unsigned short* b0 = bSrc(0);
    gload16(a0,                    As0 + wo);
    gload16(a0 + 64*512,           As0 + wo + 2048);
    gload16(b0,                    Bs0 + wo);
    gload16(b0 + (size_t)64*16384, Bs0 + wo + 2048);
    VMCNT0;
    __builtin_amdgcn_s_barrier();
    CFENCE;

    #pragma unroll 2
    for (int s = 0; s < 48; ++s){
        short* cA = (s & 1) ? As1 : As0;
        short* cB = (s & 1) ? Bs1 : Bs0;
        if (s + 1 < 48){
            short* nA = (s & 1) ? As0 : As1;
            short* nB = (s & 1) ? Bs0 : Bs1;
            const unsigned short* a1 = aSrc(s + 1);
            const unsigned short* b1 = bSrc(s + 1);
            gload16(a1,                    nA + wo);
            gload16(a1 + 64*512,           nA + wo + 2048);
            gload16(b1,                    nB + wo);
            gload16(b1 + (size_t)64*16384, nB + wo + 2048);
        }
        v8s af[4], bf[4];
        #pragma unroll
        for (int i = 0; i < 4; ++i) af[i] = *(const v8s*)&cA[(wr*64 + i*16 + fr)*32 + slot*8];
        #pragma unroll
        for (int j = 0; j < 4; ++j) bf[j] = *(const v8s*)&cB[(wc*64 + j*16 + fr)*32 + slot*8];
        __builtin_amdgcn_s_setprio(1);
        #pragma unroll
        for (int i = 0; i < 4; ++i)
            #pragma unroll
            for (int j = 0; j < 4; ++j)
                acc[i][j] = mfma16(af[i], bf[j], acc[i][j]);
        __builtin_amdgcn_s_setprio(0);
        VMCNT0;
        __builtin_amdgcn_s_barrier();
        CFENCE;
    }
    #pragma unroll
    for (int i = 0; i < 4; ++i){
        const int r = rt*128 + wr*64 + i*16 + fq*4;
        #pragma unroll
        for (int j = 0; j < 4; ++j){
            const int h = hc*128 + wc*64 + j*16 + fr;
            unsigned short* d1 = hlb + ((size_t)b*512 + r)*512 + h;
            #pragma unroll
            for (int rg = 0; rg < 4; ++rg)
                d1[(size_t)rg*512] = f32_bf16(acc[i][j][rg]);
        }
    }
}

// ---------------- s[l][m] = tanh(hlb@wawat + wb) . cw  (fused epilogue) --
__global__ __launch_bounds__(256) void k_gemm_s(
    const unsigned short* __restrict__ Hb, const unsigned short* __restrict__ Wwt,
    const float* __restrict__ wb, const float* __restrict__ cw,
    float* __restrict__ s)
{
    __shared__ __align__(16) short As[128*32];
    __shared__ __align__(16) short Bs[128*32];
    const int bm = blockIdx.x;
    const int tid = threadIdx.x;
    const int lane = tid & 63, wave = tid >> 6;
    const int wr = wave >> 1, wc = wave & 1;
    const int fr = lane & 15, fq = lane >> 4;
    const int slot = fq ^ (fr & 3) ^ ((fr >> 2) & 3);
    const int srow = tid >> 2, sw = tid & 3;
    const int gw = sw ^ (srow & 3) ^ ((srow >> 2) & 3);
    const unsigned short* Ap = Hb + ((size_t)bm*128 + srow)*512 + gw*8;
    const unsigned short* Bp = Wwt + (size_t)srow*512 + gw*8;

    v4f acc[4][4] = {};
    v8s ra0 = *(const v8s*)(Ap);
    v8s ra1 = *(const v8s*)(Ap + 64*512);
    v8s rb0 = *(const v8s*)(Bp);
    v8s rb1 = *(const v8s*)(Bp + 64*512);

    for (int kt = 0; kt < 16; ++kt){
        __syncthreads();
        *(v8s*)&As[tid*8]        = ra0;
        *(v8s*)&As[tid*8 + 2048] = ra1;
        *(v8s*)&Bs[tid*8]        = rb0;
        *(v8s*)&Bs[tid*8 + 2048] = rb1;
        __syncthreads();
        if (kt + 1 < 16){
            const unsigned short* An = Ap + (kt+1)*32;
            const unsigned short* Bn = Bp + (kt+1)*32;
            ra0 = *(const v8s*)(An); ra1 = *(const v8s*)(An + 64*512);
            rb0 = *(const v8s*)(Bn); rb1 = *(const v8s*)(Bn + 64*512);
        }
        v8s af[4], bf[4];
        #pragma unroll
        for (int i = 0; i < 4; ++i) af[i] = *(const v8s*)&As[(wr*64 + i*16 + fr)*32 + slot*8];
        #pragma unroll
        for (int i = 0; i < 4; ++i) bf[i] = *(const v8s*)&Bs[(wc*64 + i*16 + fr)*32 + slot*8];
        #pragma unroll
        for (int i = 0; i < 4; ++i)
            #pragma unroll
            for (int j = 0; j < 4; ++j)
                acc[i][j] = mfma16(af[i], bf[j], acc[i][j]);
    }
    // ---- fused tanh-dot epilogue ----
    float part[4][4];
    #pragma unroll
    for (int i = 0; i < 4; ++i)
        #pragma unroll
        for (int rg = 0; rg < 4; ++rg) part[i][rg] = 0.f;
    #pragma unroll
    for (int j = 0; j < 4; ++j){
        const int c = wc*64 + j*16 + fr;
        const bool valid = (c < 100);
        const float wbc = valid ? wb[c] : 0.f;
        const float cwc = valid ? cw[c] : 0.f;
        #pragma unroll
        for (int i = 0; i < 4; ++i)
            #pragma unroll
            for (int rg = 0; rg < 4; ++rg){
                float x = acc[i][j][rg] + wbc;
                float th;
                if (x > 15.f) th = 1.f;
                else if (x < -15.f) th = -1.f;
                else { float ex = __expf(2.f*x); th = (ex - 1.f) / (ex + 1.f); }
                part[i][rg] += th * cwc;
            }
    }
    #pragma unroll
    for (int i = 0; i < 4; ++i)
        #pragma unroll
        for (int rg = 0; rg < 4; ++rg){
            float v = part[i][rg];
            v += __shfl_xor(v, 1);
            v += __shfl_xor(v, 2);
            v += __shfl_xor(v, 4);
            v += __shfl_xor(v, 8);
            part[i][rg] = v;
        }
    float* scr = (float*)As;                          // [128 local_m][2 wc]
    __syncthreads();
    if (fr == 0){
        #pragma unroll
        for (int i = 0; i < 4; ++i)
            #pragma unroll
            for (int rg = 0; rg < 4; ++rg)
                scr[(wr*64 + i*16 + fq*4 + rg)*2 + wc] = part[i][rg];
    }
    __syncthreads();
    if (tid < 128){
        const float v = scr[tid*2] + scr[tid*2 + 1];
        const int grow = bm*128 + tid;                // 0..49151 = l*16384 + m
        s[grow] = v;
    }
}

// ---------------- final combine (fused 3-way layer softmax) -------------
__global__ void k_comb(const unsigned short* __restrict__ hlb, const float* __restrict__ s,
                       float* __restrict__ out)
{
    int idx = blockIdx.x * 256 + threadIdx.x;         // 8-elem index
    if (idx >= 16384*64) return;
    int m = idx >> 6, c8 = (idx & 63) << 3;
    float s0 = s[m], s1 = s[16384 + m], s2 = s[32768 + m];
    float m0 = fmaxf(s0, fmaxf(s1, s2));
    float e0 = __expf(s0-m0), e1 = __expf(s1-m0), e2 = __expf(s2-m0);
    float inv = 1.f / (e0 + e1 + e2);
    float v0 = e0*inv, v1 = e1*inv, v2 = e2*inv;
    const unsigned short* hp = hlb + (size_t)m*512 + c8;
    v8s a = *(const v8s*)hp;
    v8s bb = *(const v8s*)(hp + (size_t)16384*512);
    v8s cc = *(const v8s*)(hp + (size_t)2*16384*512);
    float o[8];
    #pragma unroll
    for (int u = 0; u < 8; ++u)
        o[u] = v0*bf16_f32((unsigned short)a[u])
             + v1*bf16_f32((unsigned short)bb[u])
             + v2*bf16_f32((unsigned short)cc[u]);
    float4* dst = (float4*)(out + (size_t)m*512 + c8);
    dst[0] = make_float4(o[0], o[1], o[2], o[3]);
    dst[1] = make_float4(o[4], o[5], o[6], o[7]);
}

// ------------------------------------------------------------------------
extern "C" void kernel_launch(void* const* d_in, const int* in_sizes, int n_in,
                              void* d_out, int out_size, void* d_ws, size_t ws_size,
                              hipStream_t stream)
{
    (void)in_sizes; (void)n_in; (void)out_size; (void)ws_size;
    const float* hs   = (const float*)d_in[0];
    const float* adj  = (const float*)d_in[1];
    const float* W    = (const float*)d_in[2];
    const float* aall = (const float*)d_in[3];
    const float* ww   = (const float*)d_in[4];
    const float* wb   = (const float*)d_in[5];
    const float* cw   = (const float*)d_in[6];
    float* out = (float*)d_out;
    char* ws = (char*)d_ws;

    unsigned short* Xb  = (unsigned short*)(ws);
    unsigned short* Wt  = (unsigned short*)(ws + 33554432);
    unsigned short* Wwt = (unsigned short*)(ws + 42991616);
    u64* bits           = (u64*)(ws + 43122688);
    u64* P2             = (u64*)(ws + 46268416);
    u64* P3             = (u64*)(ws + 49414144);
    unsigned short* Ht  = (unsigned short*)(ws + 52559872);
    float* f1p          = (float*)(ws + 103284736);
    float* f2p          = (float*)(ws + 104071168);
    unsigned short* att = (unsigned short*)(ws + 104857600);   // 50.3 MB
    unsigned short* hlb = (unsigned short*)(ws + 203948032);
    float* sbuf         = (float*)(ws + 52559872);    // alias Ht (dead by then)

    k_convert_x<<<8192, 256, 0, stream>>>(hs, (v8s*)Xb, 2097152);
    k_transpose_w<<<dim3(32,16,9), dim3(32,8), 0, stream>>>(W, Wt);
    k_wawat<<<256, 256, 0, stream>>>(ww, Wwt);
    k_bits<<<12288, 256, 0, stream>>>(adj, bits);
    // P2 = A*A ; P3 = A*(A*A)  (boolean product associative -> prev stays sparse)
    k_boolmm<<<192, 256, 0, stream>>>(bits, bits, P2);
    k_boolmm<<<192, 256, 0, stream>>>(bits, P2, P3);

    const u64* masks[3] = {bits, P2, P3};
    for (int l = 0; l < 3; ++l){
        k_gemm_h<<<dim3(128,4,3), 256, 0, stream>>>(Wt, Xb, Ht, aall, f1p, f2p, l);
        k_soft<<<12288, 256, 0, stream>>>(f1p, f2p, masks[l], att);
        k_pv<<<dim3(32,4,4), 256, 0, stream>>>(att, Ht,
            hlb + (size_t)l*16384*512);
    }
    k_gemm_s<<<384, 256, 0, stream>>>(hlb, Wwt, wb, cw, sbuf);
    k_comb<<<4096, 256, 0, stream>>>(hlb, sbuf, out);
}

// Round 17
// 514.508 us; speedup vs baseline: 1.0463x; 1.0463x over previous
//
#include <hip/hip_runtime.h>
#include <hip/hip_bf16.h>

typedef short v8s __attribute__((ext_vector_type(8)));
typedef float v4f __attribute__((ext_vector_type(4)));
typedef unsigned long long u64;

#define ALPHA 0.2f

__device__ inline unsigned short f32_bf16(float x){
    unsigned int u = __float_as_uint(x);
    unsigned int r = (u + 0x7fffu + ((u >> 16) & 1u)) >> 16;
    return (unsigned short)r;
}
__device__ inline float bf16_f32(unsigned short s){
    return __uint_as_float(((unsigned int)s) << 16);
}
__device__ inline v4f mfma16(v8s a, v8s b, v4f c){
    return __builtin_amdgcn_mfma_f32_16x16x32_bf16(a, b, c, 0, 0, 0);
}
// async global->LDS, 16B per lane; lds ptr must be wave-uniform base (lane*16 added by HW)
__device__ inline void gload16(const unsigned short* g, short* l){
    __builtin_amdgcn_global_load_lds((const __attribute__((address_space(1))) unsigned int*)g,
                                     (__attribute__((address_space(3))) unsigned int*)l,
                                     16, 0, 0);
}

// ---------------- conversions -------------------------------------------

__global__ void k_convert_x(const float* __restrict__ x, v8s* __restrict__ out, int n8){
    int i = blockIdx.x * 256 + threadIdx.x;
    if (i >= n8) return;
    const float4* p = (const float4*)x + (size_t)i * 2;
    float4 a = p[0], b = p[1];
    v8s r;
    r[0] = (short)f32_bf16(a.x); r[1] = (short)f32_bf16(a.y);
    r[2] = (short)f32_bf16(a.z); r[3] = (short)f32_bf16(a.w);
    r[4] = (short)f32_bf16(b.x); r[5] = (short)f32_bf16(b.y);
    r[6] = (short)f32_bf16(b.z); r[7] = (short)f32_bf16(b.w);
    out[i] = r;
}

// W_all[g][k][h] f32 -> Wt[g][h][k] bf16   (g = t*3+l, 9 x 1024 x 512)
__global__ void k_transpose_w(const float* __restrict__ W, unsigned short* __restrict__ Wt){
    __shared__ float tile[32][33];
    int g = blockIdx.z, k0 = blockIdx.x * 32, h0 = blockIdx.y * 32;
    int tx = threadIdx.x, ty = threadIdx.y;           // 32 x 8
    #pragma unroll
    for (int i = 0; i < 4; ++i)
        tile[ty + i*8][tx] = W[((size_t)g*1024 + k0 + ty + i*8)*512 + h0 + tx];
    __syncthreads();
    #pragma unroll
    for (int i = 0; i < 4; ++i){
        int h = ty + i*8;
        Wt[((size_t)g*512 + h0 + h)*1024 + k0 + tx] = f32_bf16(tile[tx][h]);
    }
}

__global__ void k_wawat(const float* __restrict__ w, unsigned short* __restrict__ wt){
    int i = blockIdx.x * 256 + threadIdx.x;           // c*512 + k
    if (i >= 128 * 512) return;
    int c = i >> 9, k = i & 511;
    wt[i] = (c < 100) ? f32_bf16(w[k*100 + c]) : (unsigned short)0;
}

// ---------------- adjacency bitsets -------------------------------------

// 4 rows per block (one per wave)
__global__ __launch_bounds__(256) void k_bits(const float* __restrict__ adj,
                                              u64* __restrict__ bits){
    int row = blockIdx.x * 4 + (threadIdx.x >> 6);    // 0..49151, t-major
    int t = row >> 14, b = (row >> 9) & 31, i = row & 511;
    const float* src = adj + (((size_t)b*3 + t)*512 + i)*512;
    int lane = threadIdx.x & 63;
    #pragma unroll
    for (int w = 0; w < 8; ++w){
        u64 word = __ballot(src[w*64 + lane] > 0.5f);
        if (lane == 0) bits[(size_t)row*8 + w] = word;
    }
}

// out_row(i) = OR over k set in prev_row(i) of base_row(k); prev kept sparse (A)
__global__ __launch_bounds__(256) void k_boolmm(const u64* __restrict__ prev,
                                                const u64* __restrict__ base,
                                                u64* __restrict__ out){
    int row = blockIdx.x * 256 + threadIdx.x;         // 0..49151
    if (row >= 49152) return;
    int tb = row >> 9;
    const u64* pr = prev + (size_t)row * 8;
    const u64* bb = base + ((size_t)tb << 9) * 8;
    ulonglong2 a0 = {0,0}, a1 = {0,0}, a2 = {0,0}, a3 = {0,0};
    #pragma unroll
    for (int w = 0; w < 8; ++w){
        u64 m = pr[w];
        const u64* bw = bb + (size_t)(w << 6) * 8;
        while (m){
            int k = __builtin_ctzll(m);
            m &= m - 1;
            const ulonglong2* br = (const ulonglong2*)(bw + (size_t)k * 8);
            ulonglong2 b0 = br[0], b1 = br[1], b2 = br[2], b3 = br[3];
            a0.x |= b0.x; a0.y |= b0.y;
            a1.x |= b1.x; a1.y |= b1.y;
            a2.x |= b2.x; a2.y |= b2.y;
            a3.x |= b3.x; a3.y |= b3.y;
        }
    }
    ulonglong2* op = (ulonglong2*)(out + (size_t)row * 8);
    op[0] = a0; op[1] = a1; op[2] = a2; op[3] = a3;
}

// ---------------- Ht = Wt @ X^T + fused f1/f2 partials -------------------
// BK=64 twin-panel: two 128x32 panels per barrier cycle (32 MFMA/drain)
__global__ __launch_bounds__(256, 4) void k_gemm_h(
    const unsigned short* __restrict__ Wt, const unsigned short* __restrict__ Xb,
    unsigned short* __restrict__ Ht, const float* __restrict__ aall,
    float* __restrict__ f1p, float* __restrict__ f2p, int l)
{
    __shared__ __align__(16) short As[128*32];
    __shared__ __align__(16) short As2[128*32];
    __shared__ __align__(16) short Bs[128*32];
    __shared__ __align__(16) short Bs2[128*32];
    const int bn = blockIdx.x, bm = blockIdx.y, t = blockIdx.z;
    const int g = t*3 + l;
    const int tid = threadIdx.x;
    const int lane = tid & 63, wave = tid >> 6;
    const int wr = wave >> 1, wc = wave & 1;
    const int fr = lane & 15, fq = lane >> 4;
    const int slot = fq ^ (fr & 3) ^ ((fr >> 2) & 3);

    const int srow = tid >> 2, sw = tid & 3;
    const int gw = sw ^ (srow & 3) ^ ((srow >> 2) & 3);   // pre-swizzled global word
    const unsigned short* Ap = Wt + ((size_t)g*512 + (size_t)bm*128 + srow)*1024 + gw*8;
    const unsigned short* Bp = Xb + ((size_t)bn*128 + srow)*1024 + gw*8;
    short* AsW  = As  + wave*512;                     // wave-uniform LDS bases
    short* As2W = As2 + wave*512;
    short* BsW  = Bs  + wave*512;
    short* Bs2W = Bs2 + wave*512;

    v4f acc[4][4] = {};

    for (int kt = 0; kt < 16; ++kt){                  // 16 double-steps over K=1024
        const unsigned short* a0 = Ap + kt*64;
        const unsigned short* b0 = Bp + kt*64;
        gload16(a0,                AsW);
        gload16(a0 + 64*1024,      AsW  + 2048);
        gload16(b0,                BsW);
        gload16(b0 + 64*1024,      BsW  + 2048);
        gload16(a0 + 32,           As2W);
        gload16(a0 + 32 + 64*1024, As2W + 2048);
        gload16(b0 + 32,           Bs2W);
        gload16(b0 + 32 + 64*1024, Bs2W + 2048);
        __syncthreads();                              // drains vmcnt -> LDS ready
        {
            v8s af[4], bf[4];
            #pragma unroll
            for (int i = 0; i < 4; ++i) af[i] = *(const v8s*)&As[(wr*64 + i*16 + fr)*32 + slot*8];
            #pragma unroll
            for (int i = 0; i < 4; ++i) bf[i] = *(const v8s*)&Bs[(wc*64 + i*16 + fr)*32 + slot*8];
            #pragma unroll
            for (int i = 0; i < 4; ++i)
                #pragma unroll
                for (int j = 0; j < 4; ++j)
                    acc[i][j] = mfma16(af[i], bf[j], acc[i][j]);
        }
        {
            v8s af[4], bf[4];
            #pragma unroll
            for (int i = 0; i < 4; ++i) af[i] = *(const v8s*)&As2[(wr*64 + i*16 + fr)*32 + slot*8];
            #pragma unroll
            for (int i = 0; i < 4; ++i) bf[i] = *(const v8s*)&Bs2[(wc*64 + i*16 + fr)*32 + slot*8];
            #pragma unroll
            for (int i = 0; i < 4; ++i)
                #pragma unroll
                for (int j = 0; j < 4; ++j)
                    acc[i][j] = mfma16(af[i], bf[j], acc[i][j]);
        }
        __syncthreads();                              // compute done before overwrite
    }
    // ---- C write ----
    #pragma unroll
    for (int i = 0; i < 4; ++i){
        const int h = bm*128 + wr*64 + i*16 + fq*4;
        #pragma unroll
        for (int j = 0; j < 4; ++j){
            const int mc = bn*128 + wc*64 + j*16 + fr;
            unsigned short* dst = Ht + ((size_t)t*512 + h)*16384 + mc;
            #pragma unroll
            for (int rg = 0; rg < 4; ++rg)
                dst[(size_t)rg*16384] = f32_bf16(acc[i][j][rg]);
        }
    }
    // ---- fused f1/f2 partial epilogue ----
    const float* a1 = aall + ((size_t)t*3 + l)*1024;
    const float* a2 = a1 + 512;
    float s1[4] = {0.f,0.f,0.f,0.f}, s2[4] = {0.f,0.f,0.f,0.f};
    #pragma unroll
    for (int i = 0; i < 4; ++i){
        #pragma unroll
        for (int rg = 0; rg < 4; ++rg){
            const int h = bm*128 + wr*64 + i*16 + fq*4 + rg;
            const float c1 = a1[h], c2 = a2[h];
            #pragma unroll
            for (int j = 0; j < 4; ++j){
                s1[j] += acc[i][j][rg]*c1;
                s2[j] += acc[i][j][rg]*c2;
            }
        }
    }
    #pragma unroll
    for (int j = 0; j < 4; ++j){
        s1[j] += __shfl_xor(s1[j], 16); s1[j] += __shfl_xor(s1[j], 32);
        s2[j] += __shfl_xor(s2[j], 16); s2[j] += __shfl_xor(s2[j], 32);
    }
    float* scr = (float*)As;                          // [2wr][2wc][4j][16fr][2] = 512 f
    __syncthreads();
    if (fq == 0){
        #pragma unroll
        for (int j = 0; j < 4; ++j){
            scr[(((wr*2 + wc)*4 + j)*16 + fr)*2 + 0] = s1[j];
            scr[(((wr*2 + wc)*4 + j)*16 + fr)*2 + 1] = s2[j];
        }
    }
    __syncthreads();
    if (tid < 256){
        const int which = tid & 1, fr2 = (tid >> 1) & 15, j2 = (tid >> 5) & 3,
                  wc2 = (tid >> 7) & 1;
        const float v = scr[(((0*2 + wc2)*4 + j2)*16 + fr2)*2 + which]
                      + scr[(((1*2 + wc2)*4 + j2)*16 + fr2)*2 + which];
        const int m = bn*128 + wc2*64 + j2*16 + fr2;
        float* dst = which ? f2p : f1p;
        dst[((size_t)bm*3 + t)*16384 + m] = v;
    }
}

// ---------------- masked softmax -> normalized bf16 att rows ------------
// one wave per attention row; sums the 4 bm-partials of f1/f2 inline
__global__ __launch_bounds__(256) void k_soft(
    const float* __restrict__ f1p, const float* __restrict__ f2p,
    const u64* __restrict__ maskP, unsigned short* __restrict__ att)
{
    const int row = blockIdx.x * 4 + (threadIdx.x >> 6);  // (t*32+b)*512 + r
    const int lane = threadIdx.x & 63;
    const int tb = row >> 9;
    const int t = tb >> 5, b = tb & 31;
    const int m1 = b*512 + (row & 511);
    float f1v = 0.f;
    #pragma unroll
    for (int bm = 0; bm < 4; ++bm)
        f1v += f1p[((size_t)bm*3 + t)*16384 + m1];
    const u64 mword = maskP[(size_t)row*8 + (lane >> 3)];
    const unsigned int mbits = (unsigned int)((mword >> ((lane & 7)*8)) & 0xffu);
    const int m2 = b*512 + lane*8;
    float f2v[8] = {0.f,0.f,0.f,0.f,0.f,0.f,0.f,0.f};
    #pragma unroll
    for (int bm = 0; bm < 4; ++bm){
        const float4* fp = (const float4*)(f2p + ((size_t)bm*3 + t)*16384 + m2);
        float4 fa = fp[0], fb = fp[1];
        f2v[0] += fa.x; f2v[1] += fa.y; f2v[2] += fa.z; f2v[3] += fa.w;
        f2v[4] += fb.x; f2v[5] += fb.y; f2v[6] += fb.z; f2v[7] += fb.w;
    }
    float p[8];
    float sm = 0.f;
    #pragma unroll
    for (int u = 0; u < 8; ++u){
        float e = f1v + f2v[u];
        e = (e >= 0.f) ? e : ALPHA*e;
        float pe = (mbits & (1u << u)) ? __expf(e) : 0.f;
        p[u] = pe; sm += pe;
    }
    sm += __shfl_xor(sm, 1);  sm += __shfl_xor(sm, 2);  sm += __shfl_xor(sm, 4);
    sm += __shfl_xor(sm, 8);  sm += __shfl_xor(sm, 16); sm += __shfl_xor(sm, 32);
    const float rinv = 1.f / (sm + 1e-30f);
    v8s pk;
    #pragma unroll
    for (int u = 0; u < 8; ++u) pk[u] = (short)f32_bf16(p[u] * rinv);
    *(v8s*)&att[(size_t)row*512 + lane*8] = pk;
}

// ---------------- PV as batched GEMM, K fused over t (K=1536) -----------
// BK=64 twin-panel; grid (32 b, 4 hc, 4 rt) -> b%8 fixes XCD (att+Ht L2-local)
__global__ __launch_bounds__(256, 4) void k_pv(
    const unsigned short* __restrict__ att, const unsigned short* __restrict__ Ht,
    unsigned short* __restrict__ hlb)
{
    __shared__ __align__(16) short As[128*32];
    __shared__ __align__(16) short As2[128*32];
    __shared__ __align__(16) short Bs[128*32];
    __shared__ __align__(16) short Bs2[128*32];
    const int b = blockIdx.x, hc = blockIdx.y, rt = blockIdx.z;
    const int tid = threadIdx.x;
    const int lane = tid & 63, wave = tid >> 6;
    const int wr = wave >> 1, wc = wave & 1;
    const int fr = lane & 15, fq = lane >> 4;
    const int slot = fq ^ (fr & 3) ^ ((fr >> 2) & 3);
    const int srow = tid >> 2, sw = tid & 3;
    const int gw = sw ^ (srow & 3) ^ ((srow >> 2) & 3);
    short* AsW  = As  + wave*512;
    short* As2W = As2 + wave*512;
    short* BsW  = Bs  + wave*512;
    short* Bs2W = Bs2 + wave*512;

    v4f acc[4][4] = {};

    for (int t = 0; t < 3; ++t){
        const unsigned short* Ap = att + ((size_t)((t*32 + b)*512 + rt*128 + srow))*512 + gw*8;
        const unsigned short* Bp = Ht + ((size_t)t*512 + hc*128 + srow)*16384 + (size_t)b*512 + gw*8;
        for (int kk = 0; kk < 8; ++kk){               // 8 double-steps over K=512
            const unsigned short* a0 = Ap + kk*64;
            const unsigned short* b0 = Bp + kk*64;
            gload16(a0,                         AsW);
            gload16(a0 + 64*512,                AsW  + 2048);
            gload16(b0,                         BsW);
            gload16(b0 + (size_t)64*16384,      BsW  + 2048);
            gload16(a0 + 32,                    As2W);
            gload16(a0 + 32 + 64*512,           As2W + 2048);
            gload16(b0 + 32,                    Bs2W);
            gload16(b0 + 32 + (size_t)64*16384, Bs2W + 2048);
            __syncthreads();
            {
                v8s af[4], bf[4];
                #pragma unroll
                for (int i = 0; i < 4; ++i) af[i] = *(const v8s*)&As[(wr*64 + i*16 + fr)*32 + slot*8];
                #pragma unroll
                for (int j = 0; j < 4; ++j) bf[j] = *(const v8s*)&Bs[(wc*64 + j*16 + fr)*32 + slot*8];
                #pragma unroll
                for (int i = 0; i < 4; ++i)
                    #pragma unroll
                    for (int j = 0; j < 4; ++j)
                        acc[i][j] = mfma16(af[i], bf[j], acc[i][j]);
            }
            {
                v8s af[4], bf[4];
                #pragma unroll
                for (int i = 0; i < 4; ++i) af[i] = *(const v8s*)&As2[(wr*64 + i*16 + fr)*32 + slot*8];
                #pragma unroll
                for (int j = 0; j < 4; ++j) bf[j] = *(const v8s*)&Bs2[(wc*64 + j*16 + fr)*32 + slot*8];
                #pragma unroll
                for (int i = 0; i < 4; ++i)
                    #pragma unroll
                    for (int j = 0; j < 4; ++j)
                        acc[i][j] = mfma16(af[i], bf[j], acc[i][j]);
            }
            __syncthreads();
        }
    }
    #pragma unroll
    for (int i = 0; i < 4; ++i){
        const int r = rt*128 + wr*64 + i*16 + fq*4;
        #pragma unroll
        for (int j = 0; j < 4; ++j){
            const int h = hc*128 + wc*64 + j*16 + fr;
            unsigned short* d1 = hlb + ((size_t)b*512 + r)*512 + h;
            #pragma unroll
            for (int rg = 0; rg < 4; ++rg)
                d1[(size_t)rg*512] = f32_bf16(acc[i][j][rg]);
        }
    }
}

// ---------------- s[l][m] = tanh(hlb@wawat + wb) . cw  (fused epilogue) --
__global__ __launch_bounds__(256) void k_gemm_s(
    const unsigned short* __restrict__ Hb, const unsigned short* __restrict__ Wwt,
    const float* __restrict__ wb, const float* __restrict__ cw,
    float* __restrict__ s)
{
    __shared__ __align__(16) short As[128*32];
    __shared__ __align__(16) short Bs[128*32];
    const int bm = blockIdx.x;
    const int tid = threadIdx.x;
    const int lane = tid & 63, wave = tid >> 6;
    const int wr = wave >> 1, wc = wave & 1;
    const int fr = lane & 15, fq = lane >> 4;
    const int slot = fq ^ (fr & 3) ^ ((fr >> 2) & 3);
    const int srow = tid >> 2, sw = tid & 3;
    const int gw = sw ^ (srow & 3) ^ ((srow >> 2) & 3);
    const unsigned short* Ap = Hb + ((size_t)bm*128 + srow)*512 + gw*8;
    const unsigned short* Bp = Wwt + (size_t)srow*512 + gw*8;

    v4f acc[4][4] = {};
    v8s ra0 = *(const v8s*)(Ap);
    v8s ra1 = *(const v8s*)(Ap + 64*512);
    v8s rb0 = *(const v8s*)(Bp);
    v8s rb1 = *(const v8s*)(Bp + 64*512);

    for (int kt = 0; kt < 16; ++kt){
        __syncthreads();
        *(v8s*)&As[tid*8]        = ra0;
        *(v8s*)&As[tid*8 + 2048] = ra1;
        *(v8s*)&Bs[tid*8]        = rb0;
        *(v8s*)&Bs[tid*8 + 2048] = rb1;
        __syncthreads();
        if (kt + 1 < 16){
            const unsigned short* An = Ap + (kt+1)*32;
            const unsigned short* Bn = Bp + (kt+1)*32;
            ra0 = *(const v8s*)(An); ra1 = *(const v8s*)(An + 64*512);
            rb0 = *(const v8s*)(Bn); rb1 = *(const v8s*)(Bn + 64*512);
        }
        v8s af[4], bf[4];
        #pragma unroll
        for (int i = 0; i < 4; ++i) af[i] = *(const v8s*)&As[(wr*64 + i*16 + fr)*32 + slot*8];
        #pragma unroll
        for (int i = 0; i < 4; ++i) bf[i] = *(const v8s*)&Bs[(wc*64 + i*16 + fr)*32 + slot*8];
        #pragma unroll
        for (int i = 0; i < 4; ++i)
            #pragma unroll
            for (int j = 0; j < 4; ++j)
                acc[i][j] = mfma16(af[i], bf[j], acc[i][j]);
    }
    // ---- fused tanh-dot epilogue ----
    float part[4][4];
    #pragma unroll
    for (int i = 0; i < 4; ++i)
        #pragma unroll
        for (int rg = 0; rg < 4; ++rg) part[i][rg] = 0.f;
    #pragma unroll
    for (int j = 0; j < 4; ++j){
        const int c = wc*64 + j*16 + fr;
        const bool valid = (c < 100);
        const float wbc = valid ? wb[c] : 0.f;
        const float cwc = valid ? cw[c] : 0.f;
        #pragma unroll
        for (int i = 0; i < 4; ++i)
            #pragma unroll
            for (int rg = 0; rg < 4; ++rg){
                float x = acc[i][j][rg] + wbc;
                float th;
                if (x > 15.f) th = 1.f;
                else if (x < -15.f) th = -1.f;
                else { float ex = __expf(2.f*x); th = (ex - 1.f) / (ex + 1.f); }
                part[i][rg] += th * cwc;
            }
    }
    #pragma unroll
    for (int i = 0; i < 4; ++i)
        #pragma unroll
        for (int rg = 0; rg < 4; ++rg){
            float v = part[i][rg];
            v += __shfl_xor(v, 1);
            v += __shfl_xor(v, 2);
            v += __shfl_xor(v, 4);
            v += __shfl_xor(v, 8);
            part[i][rg] = v;
        }
    float* scr = (float*)As;                          // [128 local_m][2 wc]
    __syncthreads();
    if (fr == 0){
        #pragma unroll
        for (int i = 0; i < 4; ++i)
            #pragma unroll
            for (int rg = 0; rg < 4; ++rg)
                scr[(wr*64 + i*16 + fq*4 + rg)*2 + wc] = part[i][rg];
    }
    __syncthreads();
    if (tid < 128){
        const float v = scr[tid*2] + scr[tid*2 + 1];
        const int grow = bm*128 + tid;                // 0..49151 = l*16384 + m
        s[grow] = v;
    }
}

// ---------------- final combine (fused 3-way layer softmax) -------------
__global__ void k_comb(const unsigned short* __restrict__ hlb, const float* __restrict__ s,
                       float* __restrict__ out)
{
    int idx = blockIdx.x * 256 + threadIdx.x;         // 8-elem index
    if (idx >= 16384*64) return;
    int m = idx >> 6, c8 = (idx & 63) << 3;
    float s0 = s[m], s1 = s[16384 + m], s2 = s[32768 + m];
    float m0 = fmaxf(s0, fmaxf(s1, s2));
    float e0 = __expf(s0-m0), e1 = __expf(s1-m0), e2 = __expf(s2-m0);
    float inv = 1.f / (e0 + e1 + e2);
    float v0 = e0*inv, v1 = e1*inv, v2 = e2*inv;
    const unsigned short* hp = hlb + (size_t)m*512 + c8;
    v8s a = *(const v8s*)hp;
    v8s bb = *(const v8s*)(hp + (size_t)16384*512);
    v8s cc = *(const v8s*)(hp + (size_t)2*16384*512);
    float o[8];
    #pragma unroll
    for (int u = 0; u < 8; ++u)
        o[u] = v0*bf16_f32((unsigned short)a[u])
             + v1*bf16_f32((unsigned short)bb[u])
             + v2*bf16_f32((unsigned short)cc[u]);
    float4* dst = (float4*)(out + (size_t)m*512 + c8);
    dst[0] = make_float4(o[0], o[1], o[2], o[3]);
    dst[1] = make_float4(o[4], o[5], o[6], o[7]);
}

// ------------------------------------------------------------------------
extern "C" void kernel_launch(void* const* d_in, const int* in_sizes, int n_in,
                              void* d_out, int out_size, void* d_ws, size_t ws_size,
                              hipStream_t stream)
{
    (void)in_sizes; (void)n_in; (void)out_size; (void)ws_size;
    const float* hs   = (const float*)d_in[0];
    const float* adj  = (const float*)d_in[1];
    const float* W    = (const float*)d_in[2];
    const float* aall = (const float*)d_in[3];
    const float* ww   = (const float*)d_in[4];
    const float* wb   = (const float*)d_in[5];
    const float* cw   = (const float*)d_in[6];
    float* out = (float*)d_out;
    char* ws = (char*)d_ws;

    unsigned short* Xb  = (unsigned short*)(ws);
    unsigned short* Wt  = (unsigned short*)(ws + 33554432);
    unsigned short* Wwt = (unsigned short*)(ws + 42991616);
    u64* bits           = (u64*)(ws + 43122688);
    u64* P2             = (u64*)(ws + 46268416);
    u64* P3             = (u64*)(ws + 49414144);
    unsigned short* Ht  = (unsigned short*)(ws + 52559872);
    float* f1p          = (float*)(ws + 103284736);
    float* f2p          = (float*)(ws + 104071168);
    unsigned short* att = (unsigned short*)(ws + 104857600);   // 50.3 MB
    unsigned short* hlb = (unsigned short*)(ws + 203948032);
    float* sbuf         = (float*)(ws + 52559872);    // alias Ht (dead by then)

    k_convert_x<<<8192, 256, 0, stream>>>(hs, (v8s*)Xb, 2097152);
    k_transpose_w<<<dim3(32,16,9), dim3(32,8), 0, stream>>>(W, Wt);
    k_wawat<<<256, 256, 0, stream>>>(ww, Wwt);
    k_bits<<<12288, 256, 0, stream>>>(adj, bits);
    // P2 = A*A ; P3 = A*(A*A)  (boolean product associative -> prev stays sparse)
    k_boolmm<<<192, 256, 0, stream>>>(bits, bits, P2);
    k_boolmm<<<192, 256, 0, stream>>>(bits, P2, P3);

    const u64* masks[3] = {bits, P2, P3};
    for (int l = 0; l < 3; ++l){
        k_gemm_h<<<dim3(128,4,3), 256, 0, stream>>>(Wt, Xb, Ht, aall, f1p, f2p, l);
        k_soft<<<12288, 256, 0, stream>>>(f1p, f2p, masks[l], att);
        k_pv<<<dim3(32,4,4), 256, 0, stream>>>(att, Ht,
            hlb + (size_t)l*16384*512);
    }
    k_gemm_s<<<384, 256, 0, stream>>>(hlb, Wwt, wb, cw, sbuf);
    k_comb<<<4096, 256, 0, stream>>>(hlb, sbuf, out);
}